// Round 1
// 96.128 us; speedup vs baseline: 1.0379x; 1.0379x over previous
//
#include <hip/hip_runtime.h>
#include <hip/hip_bf16.h>
#include <stdint.h>

#define N_TOT  8192
#define BHALF  4096
#define DDIM   128
#define NSPLIT 16

typedef short bf16x8 __attribute__((ext_vector_type(8)));
typedef float f32x4  __attribute__((ext_vector_type(4)));

__device__ __forceinline__ float ex2(float x) { return __builtin_amdgcn_exp2f(x); }

#define SCALE_C 3.798282440185f   /* sqrt(10*log2(e)): MFMA emits t = s*log2e */

__device__ __forceinline__ ushort2 cvt2(float a, float b) {
    __hip_bfloat162 h = __float22bfloat162_rn(make_float2(a, b));
    return *reinterpret_cast<ushort2*>(&h);
}

__device__ __forceinline__ bf16x8 cvt8(float4 lo, float4 hi) {
    union { bf16x8 v; ushort2 u[4]; } r;
    r.u[0] = cvt2(lo.x * SCALE_C, lo.y * SCALE_C);
    r.u[1] = cvt2(lo.z * SCALE_C, lo.w * SCALE_C);
    r.u[2] = cvt2(hi.x * SCALE_C, hi.y * SCALE_C);
    r.u[3] = cvt2(hi.z * SCALE_C, hi.w * SCALE_C);
    return r.v;
}

__device__ __forceinline__ void gload16(const void* g, void* l) {
    __builtin_amdgcn_global_load_lds(
        (const __attribute__((address_space(1))) void*)g,
        (__attribute__((address_space(3))) void*)l, 16, 0, 0);
}

// K0: z fp32 -> zb bf16 (*SCALE_C pre-folded), row-major 128/row, with the
// 16B group g of each row stored at slot g^(row&7) (pre-applied XOR swizzle:
// linear global_load_lds dest + swizzled source == swizzled LDS, rule #21).
__launch_bounds__(256)
__global__ void k_prep(const float* __restrict__ zi, const float* __restrict__ zj,
                       unsigned short* __restrict__ zb, float* __restrict__ out) {
    if (blockIdx.x == 0 && threadIdx.x == 0) out[0] = 0.f;  // init for k_finish atomics
    int gid = blockIdx.x * 256 + threadIdx.x;               // 8192 rows x 16 groups
    int row = gid >> 4, g = gid & 15;
    const float* rp = (row < BHALF) ? zi + row * DDIM : zj + (row - BHALF) * DDIM;
    float4 lo = *reinterpret_cast<const float4*>(rp + g * 8);
    float4 hi = *reinterpret_cast<const float4*>(rp + g * 8 + 4);
    int slot = g ^ (row & 7);
    *reinterpret_cast<bf16x8*>(&zb[row * DDIM + slot * 8]) = cvt8(lo, hi);
}

// K1: streaming online-logsumexp over sim = (z z^T)/T rows, bf16 MFMA.
// Grid 512 = 32 row-blocks x 16 col-splits (512 cols each). Block: 8 waves
// of 32 rows. Staging is pure DMA (global_load_lds x2/thread/chunk) from the
// pre-swizzled bf16 array; online update batched over the full 64-col chunk.
__launch_bounds__(512, 4)
__global__ void k_main(const unsigned short* __restrict__ zb,
                       float* __restrict__ pm, float* __restrict__ pl) {
    __shared__ unsigned short lds[2][64 * 128];   // 2 x 16 KB
    const int tid = threadIdx.x;
    const int w = tid >> 6, lane = tid & 63;
    const int q = lane >> 4, ln = lane & 15;
    const int rb = blockIdx.x >> 4, cs = blockIdx.x & 15;
    const int rowBase = rb * 256 + w * 32;
    const int colBase = cs * 512;

    // A fragments: direct bf16 16B loads from swizzled zb (no cvt).
    bf16x8 afr[2][4];
    #pragma unroll
    for (int s = 0; s < 2; ++s) {
        int row = rowBase + s * 16 + ln;
        const unsigned short* rp = zb + row * DDIM;
        int rx = row & 7;
        #pragma unroll
        for (int kc = 0; kc < 4; ++kc)
            afr[s][kc] = *reinterpret_cast<const bf16x8*>(rp + ((kc * 4 + q) ^ rx) * 8);
    }

    float m[2][4], l[2][4];
    #pragma unroll
    for (int s = 0; s < 2; ++s)
        #pragma unroll
        for (int r = 0; r < 4; ++r) { m[s][r] = -1e38f; l[s][r] = 0.f; }

    // Per chunk: 16 KB = 1024 lanes x 16 B. LDS dest is wave-uniform
    // (it*8192 + w*1024 bytes); HW adds lane*16. Global src carries tid.
#define STAGE(B, CH) do {                                                     \
        const unsigned short* sp_ = zb + (colBase + (CH) * 64) * DDIM;        \
        gload16(sp_ + (0 * 512 + tid) * 8, &lds[B][0 * 4096 + w * 512]);      \
        gload16(sp_ + (1 * 512 + tid) * 8, &lds[B][1 * 4096 + w * 512]);      \
    } while (0)

    STAGE(0, 0);
    __syncthreads();                 // compiler drains vmcnt before s_barrier

    for (int ch = 0; ch < 8; ++ch) {
        const unsigned short* buf = lds[ch & 1];
        if (ch < 7) STAGE((ch + 1) & 1, ch + 1);   // DMA prefetch under compute

        f32x4 acc[2][4];
        #pragma unroll
        for (int s = 0; s < 2; ++s)
            #pragma unroll
            for (int ct = 0; ct < 4; ++ct) acc[s][ct] = (f32x4){0.f, 0.f, 0.f, 0.f};

        #pragma unroll
        for (int ct = 0; ct < 4; ++ct) {           // 4 x 16-col tiles, 32 MFMA/chunk
            bf16x8 bfr[4];
            #pragma unroll
            for (int kc = 0; kc < 4; ++kc) {
                int slot = (q + 4 * kc) ^ (ln & 7);
                bfr[kc] = *reinterpret_cast<const bf16x8*>(
                    &buf[(ct * 16 + ln) * 128 + slot * 8]);
            }
            #pragma unroll
            for (int s = 0; s < 2; ++s)
                #pragma unroll
                for (int kc = 0; kc < 4; ++kc)
                    acc[s][ct] = __builtin_amdgcn_mfma_f32_16x16x32_bf16(
                        afr[s][kc], bfr[kc], acc[s][ct], 0, 0, 0);
        }

        const int c0 = colBase + ch * 64;
        #pragma unroll
        for (int s = 0; s < 2; ++s) {
            const int rt = rowBase + s * 16;
            #pragma unroll
            for (int ct = 0; ct < 4; ++ct) {       // diag mask, static ct (rule #20)
                if (rt == c0 + ct * 16) {
                    #pragma unroll
                    for (int r = 0; r < 4; ++r)
                        if (ln == q * 4 + r) acc[s][ct][r] = -__builtin_inff();
                }
            }
            #pragma unroll
            for (int r = 0; r < 4; ++r) {          // 64-col batched online update
                float t0 = acc[s][0][r], t1 = acc[s][1][r];
                float t2 = acc[s][2][r], t3 = acc[s][3][r];
                float mo = m[s][r];
                float mn = fmaxf(fmaxf(fmaxf(t0, t1), fmaxf(t2, t3)), mo);
                float sc = ex2(mo - mn);
                float pv = (ex2(t0 - mn) + ex2(t1 - mn)) + (ex2(t2 - mn) + ex2(t3 - mn));
                l[s][r] = fmaf(l[s][r], sc, pv);
                m[s][r] = mn;
            }
        }
        __syncthreads();
    }
#undef STAGE

    // merge (m,l) across the 16 lanes (same quad) holding each row
    #pragma unroll
    for (int s = 0; s < 2; ++s) {
        #pragma unroll
        for (int r = 0; r < 4; ++r) {
            float mm = m[s][r], ll = l[s][r];
            #pragma unroll
            for (int msk = 1; msk < 16; msk <<= 1) {
                float om = __shfl_xor(mm, msk, 64);
                float ol = __shfl_xor(ll, msk, 64);
                float mn = fmaxf(mm, om);
                ll = ll * ex2(mm - mn) + ol * ex2(om - mn);
                mm = mn;
            }
            if (ln == 0) {
                int row = rowBase + s * 16 + q * 4 + r;
                pm[cs * N_TOT + row] = mm;
                pl[cs * N_TOT + row] = ll;
            }
        }
    }
}

// K2: per-row merge of 16 col-split partials, pos computed inline (fp32
// exact), extra exp(pos) term, block-reduce, atomicAdd into out.
__global__ void k_finish(const float* __restrict__ zi, const float* __restrict__ zj,
                         const float* __restrict__ pm, const float* __restrict__ pl,
                         float* __restrict__ out) {
    int row = blockIdx.x * 256 + threadIdx.x;
    int pr  = row & (BHALF - 1);
    const float4* a = reinterpret_cast<const float4*>(zi + pr * DDIM);
    const float4* b = reinterpret_cast<const float4*>(zj + pr * DDIM);
    float acc = 0.f;
    #pragma unroll
    for (int k = 0; k < 32; ++k) {
        float4 x = a[k], y = b[k];
        acc += x.x * y.x + x.y * y.y + x.z * y.z + x.w * y.w;
    }
    float p  = 10.f * acc;
    float tp = p * 1.4426950408889634f;
    float mm[NSPLIT];
    float M = tp;
    #pragma unroll
    for (int j = 0; j < NSPLIT; ++j) {
        mm[j] = pm[j * N_TOT + row];
        M = fmaxf(M, mm[j]);
    }
    float S = ex2(tp - M);
    #pragma unroll
    for (int j = 0; j < NSPLIT; ++j)
        S += pl[j * N_TOT + row] * ex2(mm[j] - M);
    float lse = (M + __log2f(S)) * 0.6931471805599453f;
    float li  = lse - p;
    #pragma unroll
    for (int msk = 32; msk; msk >>= 1) li += __shfl_xor(li, msk, 64);
    __shared__ float red[4];
    if ((threadIdx.x & 63) == 0) red[threadIdx.x >> 6] = li;
    __syncthreads();
    if (threadIdx.x == 0)
        atomicAdd(out, (red[0] + red[1] + red[2] + red[3]) * (1.f / 8192.f));
}

extern "C" void kernel_launch(void* const* d_in, const int* in_sizes, int n_in,
                              void* d_out, int out_size, void* d_ws, size_t ws_size,
                              hipStream_t stream) {
    const float* zi = (const float*)d_in[0];
    const float* zj = (const float*)d_in[1];
    float* out = (float*)d_out;
    char* ws = (char*)d_ws;

    unsigned short* zb = (unsigned short*)ws;                  // 8192*128*2 = 2 MB
    float* pm = (float*)(ws + (size_t)N_TOT * DDIM * 2);       // 512 KB
    float* pl = pm + NSPLIT * N_TOT;                           // 512 KB

    hipLaunchKernelGGL(k_prep,   dim3(512), dim3(256), 0, stream, zi, zj, zb, out);
    hipLaunchKernelGGL(k_main,   dim3(512), dim3(512), 0, stream, zb, pm, pl);
    hipLaunchKernelGGL(k_finish, dim3(32),  dim3(256), 0, stream, zi, zj, pm, pl, out);
}